// Round 2
// baseline (868.447 us; speedup 1.0000x reference)
//
#include <hip/hip_runtime.h>
#include <math.h>

// Problem constants (fixed by setup_inputs)
constexpr int B    = 4;
constexpr int N    = 8192;
constexpr int K    = 32;
constexpr int COUT = 64;
constexpr int E    = B * N * K;     // 1048576 edges
constexpr int BN   = B * N;         // 32768
constexpr int PERB = N * K;         // 262144 elements per (b,o) norm group
constexpr float EPS   = 1e-5f;
constexpr float SLOPE = 0.1f;

// bf16 <-> f32 helpers (RTNE on the way down)
__device__ __forceinline__ float bf2f(unsigned int h) {
    union { unsigned int u; float f; } v; v.u = h << 16; return v.f;
}
__device__ __forceinline__ unsigned int f2bf(float f) {
    union { unsigned int u; float f; } v; v.f = f;
    return (v.u + 0x7FFFu + ((v.u >> 16) & 1u)) >> 16;   // RTNE
}
__device__ __forceinline__ float lrelu(float z) {
    return fmaxf(z, 0.f) + SLOPE * fminf(z, 0.f);
}

// ---------------------------------------------------------------------------
// Zero the small scratch region (flag + sums). Avoids hipMemsetAsync entirely.
__global__ void zero_k(float* __restrict__ s) {
    for (int j = threadIdx.x; j < 4096; j += 256) s[j] = 0.f;
}

// ---------------------------------------------------------------------------
// Detect int32 vs int64 storage of `edges`. Values < 32768, so if int64 the
// hi-words of the first 64 elements are all zero; if int32 they're random
// edge indices (P(all zero) ~ 0). flag != 0 => int32.
__global__ void detect_i32(const unsigned int* __restrict__ w, int* __restrict__ flag) {
    if (w[2 * threadIdx.x + 1] != 0u) atomicOr(flag, 1);
}

// ---------------------------------------------------------------------------
// Layer 1: gather + concat + (64x35) matmul. 2 edges per thread.
// Y layout: bf16, Y[o*E + e].
__global__ __launch_bounds__(256) void stage1(
        const float* __restrict__ signal,   // (BN, 32)
        const void*  __restrict__ edges,
        const float* __restrict__ ef,       // (E, 3)
        const float* __restrict__ W1,       // (64, 35)
        unsigned short* __restrict__ Y,
        const int* __restrict__ flag) {
    const int t  = blockIdx.x * 256 + threadIdx.x;   // pair index
    const int e0 = t * 2;
    long long i0, i1;
    if (*flag) {
        i0 = ((const int*)edges)[e0];
        i1 = ((const int*)edges)[e0 + 1];
    } else {
        i0 = ((const long long*)edges)[e0];
        i1 = ((const long long*)edges)[e0 + 1];
    }

    float a0[35], a1[35];
    const float4* s0 = (const float4*)signal + i0 * 8;
    const float4* s1 = (const float4*)signal + i1 * 8;
#pragma unroll
    for (int j = 0; j < 8; ++j) {
        float4 v = s0[j];
        a0[4 * j] = v.x; a0[4 * j + 1] = v.y; a0[4 * j + 2] = v.z; a0[4 * j + 3] = v.w;
        float4 w = s1[j];
        a1[4 * j] = w.x; a1[4 * j + 1] = w.y; a1[4 * j + 2] = w.z; a1[4 * j + 3] = w.w;
    }
#pragma unroll
    for (int j = 0; j < 3; ++j) {
        a0[32 + j] = ef[e0 * 3 + j];
        a1[32 + j] = ef[e0 * 3 + 3 + j];
    }

    for (int o = 0; o < COUT; ++o) {
        float x0 = 0.f, x1 = 0.f;
#pragma unroll
        for (int c = 0; c < 35; ++c) {
            float w = W1[o * 35 + c];                 // uniform -> s_load
            x0 += w * a0[c]; x1 += w * a1[c];
        }
        ((unsigned int*)(Y + (size_t)o * E))[t] = f2bf(x0) | (f2bf(x1) << 16);
    }
}

// ---------------------------------------------------------------------------
// Per-(b,o) sum / sumsq over PERB contiguous bf16 elements. 8 segs per group.
__global__ __launch_bounds__(256) void stats_k(const unsigned short* __restrict__ Y,
                                               float* __restrict__ sums) {
    const int g   = blockIdx.x >> 3;   // g = o*4 + b
    const int seg = blockIdx.x & 7;
    const uint4* p = (const uint4*)(Y + (size_t)g * PERB + (size_t)seg * (PERB / 8));
    float s = 0.f, s2 = 0.f;
    // seg = 32768 bf16 = 4096 uint4; 256 threads x 16
    for (int i = threadIdx.x; i < 4096; i += 256) {
        uint4 v = p[i];
        unsigned int ws[4] = {v.x, v.y, v.z, v.w};
#pragma unroll
        for (int j = 0; j < 4; ++j) {
            float f0 = bf2f(ws[j] & 0xFFFFu), f1 = bf2f(ws[j] >> 16);
            s  += f0 + f1;
            s2 += f0 * f0 + f1 * f1;
        }
    }
    __shared__ float red[512];
    red[threadIdx.x]       = s;
    red[256 + threadIdx.x] = s2;
    __syncthreads();
    for (int st = 128; st > 0; st >>= 1) {
        if (threadIdx.x < st) {
            red[threadIdx.x]       += red[threadIdx.x + st];
            red[256 + threadIdx.x] += red[256 + threadIdx.x + st];
        }
        __syncthreads();
    }
    if (threadIdx.x == 0) {
        atomicAdd(&sums[g * 2 + 0], red[0]);
        atomicAdd(&sums[g * 2 + 1], red[256]);
    }
}

// ---------------------------------------------------------------------------
// Finalize stats -> per-(b,o) scale/shift (affine folded with norm).
__global__ void finalize_k(const float* __restrict__ sums,
                           const float* __restrict__ gamma,
                           const float* __restrict__ beta,
                           float* __restrict__ scale,
                           float* __restrict__ shift) {
    const int g = threadIdx.x;          // 256
    const float inv_n = 1.f / (float)PERB;
    float mean = sums[g * 2 + 0] * inv_n;
    float var  = sums[g * 2 + 1] * inv_n - mean * mean;
    float inv  = rsqrtf(var + EPS);
    int o = g >> 2, b = g & 3;
    float sc = gamma[o] * inv;
    scale[b * COUT + o] = sc;
    shift[b * COUT + o] = beta[o] - mean * sc;
}

// ---------------------------------------------------------------------------
// Layers 2/3: in-place  Y[o] = sum_c W[o,c]*lrelu(Y[c]*sc_c + sh_c).
// 2 edges per thread; all reads complete before first write (alias-safe).
__global__ __launch_bounds__(256) void stage23(
        unsigned short* Y,                      // no restrict: in-place
        const float* __restrict__ W,            // (64, 64)
        const float* __restrict__ scale,        // (B, 64)
        const float* __restrict__ shift) {
    const int t = blockIdx.x * 256 + threadIdx.x;    // pair index
    const int b = (blockIdx.x * 512) >> 18;          // block-uniform (PERB=2^18)

    float a0[COUT], a1[COUT];
#pragma unroll
    for (int c = 0; c < COUT; ++c) {
        unsigned int v = ((const unsigned int*)(Y + (size_t)c * E))[t];
        float sc = scale[b * COUT + c], sh = shift[b * COUT + c];
        a0[c] = lrelu(bf2f(v & 0xFFFFu) * sc + sh);
        a1[c] = lrelu(bf2f(v >> 16)     * sc + sh);
    }
    for (int o = 0; o < COUT; ++o) {
        float x0 = 0.f, x1 = 0.f;
#pragma unroll
        for (int c = 0; c < COUT; ++c) {
            float w = W[o * COUT + c];               // uniform -> s_load
            x0 += w * a0[c]; x1 += w * a1[c];
        }
        ((unsigned int*)(Y + (size_t)o * E))[t] = f2bf(x0) | (f2bf(x1) << 16);
    }
}

// ---------------------------------------------------------------------------
// Final: per-(b,o) affine-normalize, max over K (handle sc sign), one lrelu.
__global__ __launch_bounds__(256) void pool_k(
        const unsigned short* __restrict__ Y,
        const float* __restrict__ scale,
        const float* __restrict__ shift,
        float* __restrict__ out) {
    const int bn = blockIdx.x * 256 + threadIdx.x;   // 0..BN-1
    const int b  = (blockIdx.x * 256) >> 13;         // N=8192 per batch
    const int o0 = blockIdx.y * 8;
    float r[8];
#pragma unroll
    for (int oi = 0; oi < 8; ++oi) {
        const int o = o0 + oi;
        const float sc = scale[b * COUT + o];
        const float sh = shift[b * COUT + o];
        const uint4* p = (const uint4*)(Y + (size_t)o * E + (size_t)bn * K);
        float mx = -1e30f, mn = 1e30f;
#pragma unroll
        for (int j = 0; j < 4; ++j) {                // K=32 bf16 = 4 uint4
            uint4 v = p[j];
            unsigned int ws[4] = {v.x, v.y, v.z, v.w};
#pragma unroll
            for (int q = 0; q < 4; ++q) {
                float f0 = bf2f(ws[q] & 0xFFFFu), f1 = bf2f(ws[q] >> 16);
                mx = fmaxf(mx, fmaxf(f0, f1));
                mn = fminf(mn, fminf(f0, f1));
            }
        }
        float m = (sc >= 0.f ? mx : mn) * sc + sh;
        r[oi] = lrelu(m);
    }
    float4* q = (float4*)(out + (size_t)bn * COUT + o0);
    q[0] = make_float4(r[0], r[1], r[2], r[3]);
    q[1] = make_float4(r[4], r[5], r[6], r[7]);
}

// ---------------------------------------------------------------------------
extern "C" void kernel_launch(void* const* d_in, const int* in_sizes, int n_in,
                              void* d_out, int out_size, void* d_ws, size_t ws_size,
                              hipStream_t stream) {
    const float* signal = (const float*)d_in[0];
    const void*  edges  = d_in[1];
    const float* ef     = (const float*)d_in[2];
    // d_in[3] = k (scalar, unused; K hard-coded)
    const float* W1 = (const float*)d_in[4];
    const float* g1 = (const float*)d_in[5];
    const float* b1 = (const float*)d_in[6];
    const float* W2 = (const float*)d_in[7];
    const float* g2 = (const float*)d_in[8];
    const float* b2 = (const float*)d_in[9];
    const float* W3 = (const float*)d_in[10];
    const float* g3 = (const float*)d_in[11];
    const float* b3 = (const float*)d_in[12];
    float* out = (float*)d_out;

    // Workspace: bf16 Y (134.2 MB) first, small scratch after.
    unsigned short* Y = (unsigned short*)d_ws;
    const size_t YBYTES = (size_t)E * COUT * sizeof(unsigned short);  // 134,217,728
    float* scratch = (float*)((char*)d_ws + YBYTES);
    int*   flag  = (int*)scratch;                 // [0]
    float* sums0 = scratch + 16;                  // 512 floats each
    float* sums1 = scratch + 16 + 512;
    float* sums2 = scratch + 16 + 1024;
    float* sc0 = scratch + 1600;  float* sh0 = sc0 + 256;
    float* sc1 = scratch + 2112;  float* sh1 = sc1 + 256;
    float* sc2 = scratch + 2624;  float* sh2 = sc2 + 256;

    zero_k<<<1, 256, 0, stream>>>(scratch);
    detect_i32<<<1, 64, 0, stream>>>((const unsigned int*)edges, flag);

    const int PBLK = E / 2 / 256;   // 2048 blocks (2 edges/thread)
    stage1<<<PBLK, 256, 0, stream>>>(signal, edges, ef, W1, Y, flag);

    stats_k<<<256 * 8, 256, 0, stream>>>(Y, sums0);
    finalize_k<<<1, 256, 0, stream>>>(sums0, g1, b1, sc0, sh0);

    stage23<<<PBLK, 256, 0, stream>>>(Y, W2, sc0, sh0);
    stats_k<<<256 * 8, 256, 0, stream>>>(Y, sums1);
    finalize_k<<<1, 256, 0, stream>>>(sums1, g2, b2, sc1, sh1);

    stage23<<<PBLK, 256, 0, stream>>>(Y, W3, sc1, sh1);
    stats_k<<<256 * 8, 256, 0, stream>>>(Y, sums2);
    finalize_k<<<1, 256, 0, stream>>>(sums2, g3, b3, sc2, sh2);

    pool_k<<<dim3(BN / 256, 8), 256, 0, stream>>>(Y, sc2, sh2, out);
}

// Round 3
// 292.515 us; speedup vs baseline: 2.9689x; 2.9689x over previous
//
#include <hip/hip_runtime.h>
#include <math.h>

// Problem constants (fixed by setup_inputs)
constexpr int B    = 4;
constexpr int N    = 8192;
constexpr int COUT = 64;
constexpr int E    = B * N * 32;      // 1048576 edges
constexpr int PERB = N * 32;          // 262144 elements per (b,o) norm group
constexpr int TILES  = E / 16;        // 65536 16-edge tiles
constexpr int BLOCKS = 1024;          // 256 blocks per batch
constexpr int TPB    = TILES / BLOCKS;// 64 tiles per block (16 per wave)
constexpr float EPS   = 1e-5f;
constexpr float SLOPE = 0.1f;

// Tiled-pack activation layout (bf16):
//   addr(c, e) = (e>>4)*1024 + (c>>3)*128 + (e&15)*8 + (c&7)    [ushort units]
// -> MFMA B-frag (8 ch of one edge) = one 16B load; C-store = 8B per m-tile.

typedef __attribute__((ext_vector_type(8))) short short8;
typedef __attribute__((ext_vector_type(4))) float f32x4;
#define MFMA16 __builtin_amdgcn_mfma_f32_16x16x32_bf16

union S8 { short8 s; unsigned int u[4]; };

__device__ __forceinline__ float bflo(unsigned int u) {
    union { unsigned int x; float f; } v; v.x = u << 16; return v.f;
}
__device__ __forceinline__ float bfhi(unsigned int u) {
    union { unsigned int x; float f; } v; v.x = u & 0xFFFF0000u; return v.f;
}
__device__ __forceinline__ unsigned int f2bf(float f) {
    union { unsigned int u; float f; } v; v.f = f;
    return (v.u + 0x7FFFu + ((v.u >> 16) & 1u)) >> 16;   // RTNE
}
__device__ __forceinline__ unsigned int pk2(float a, float b) {
    return f2bf(a) | (f2bf(b) << 16);
}
__device__ __forceinline__ short8 pack8(const float* f) {
    S8 r;
#pragma unroll
    for (int i = 0; i < 4; ++i) r.u[i] = pk2(f[2 * i], f[2 * i + 1]);
    return r.s;
}
// unpack 8 bf16, apply per-channel scale/shift + leaky relu, repack bf16
__device__ __forceinline__ short8 xform(uint4 raw, const float* sc, const float* sh) {
    unsigned int w[4] = {raw.x, raw.y, raw.z, raw.w};
    float z[8];
#pragma unroll
    for (int i = 0; i < 4; ++i) {
        z[2 * i]     = fmaf(bflo(w[i]), sc[2 * i],     sh[2 * i]);
        z[2 * i + 1] = fmaf(bfhi(w[i]), sc[2 * i + 1], sh[2 * i + 1]);
    }
#pragma unroll
    for (int j = 0; j < 8; ++j) z[j] = fmaxf(z[j], 0.f) + SLOPE * fminf(z[j], 0.f);
    S8 r;
#pragma unroll
    for (int i = 0; i < 4; ++i) r.u[i] = pk2(z[2 * i], z[2 * i + 1]);
    return r.s;
}

// ---------------------------------------------------------------------------
__global__ void detect_i32(const unsigned int* __restrict__ w, int* __restrict__ flag) {
    unsigned long long m = __ballot(w[2 * threadIdx.x + 1] != 0u);
    if (threadIdx.x == 0) *flag = (m != 0ull) ? 1 : 0;
}

// ---------------------------------------------------------------------------
// Shared epilogue: per-(b,o) sum/sumsq partials -> partials[block][o*2+{0,1}]
__device__ __forceinline__ void stats_epilogue(
        float (&sacc)[4][4], float (&s2acc)[4][4],
        int tid, int wv, int col, int quad,
        float* __restrict__ partials) {
    __shared__ float lds[2][4][64];
#pragma unroll
    for (int m = 0; m < 4; ++m)
#pragma unroll
        for (int r = 0; r < 4; ++r) {
            float s = sacc[m][r], s2 = s2acc[m][r];
#pragma unroll
            for (int d = 1; d < 16; d <<= 1) {
                s  += __shfl_xor(s,  d, 16);
                s2 += __shfl_xor(s2, d, 16);
            }
            if (col == 0) {
                int o = m * 16 + quad * 4 + r;
                lds[0][wv][o] = s;
                lds[1][wv][o] = s2;
            }
        }
    __syncthreads();
    if (tid < 64) {
        float s  = lds[0][0][tid] + lds[0][1][tid] + lds[0][2][tid] + lds[0][3][tid];
        float s2 = lds[1][0][tid] + lds[1][1][tid] + lds[1][2][tid] + lds[1][3][tid];
        ((float2*)(partials + (size_t)blockIdx.x * 128))[tid] = make_float2(s, s2);
    }
}

// ---------------------------------------------------------------------------
// Layer 1: gather + concat + MFMA (K=35 padded to 64). Writes TP layout + stats.
__global__ __launch_bounds__(256) void mfma_stage1(
        const float* __restrict__ signal,   // (BN, 32)
        const void*  __restrict__ edges,
        const float* __restrict__ ef,       // (E, 3)
        const float* __restrict__ W1,       // (64, 35)
        unsigned short* __restrict__ Y,
        const int* __restrict__ flag,
        float* __restrict__ partials) {
    const int tid = threadIdx.x, lane = tid & 63, wv = tid >> 6;
    const int col = lane & 15, quad = lane >> 4;

    short8 afrag[4][2];
#pragma unroll
    for (int m = 0; m < 4; ++m) {
        const float* wr = W1 + (m * 16 + col) * 35;
        float f[8];
#pragma unroll
        for (int j = 0; j < 8; ++j) f[j] = wr[quad * 8 + j];
        afrag[m][0] = pack8(f);
#pragma unroll
        for (int j = 0; j < 8; ++j) f[j] = (quad == 0 && j < 3) ? wr[32 + j] : 0.f;
        afrag[m][1] = pack8(f);
    }
    const bool is32 = (*flag != 0);
    const int* ip = (const int*)edges;
    const long long* lp = (const long long*)edges;

    float sacc[4][4] = {{0.f}}, s2acc[4][4] = {{0.f}};
    const int tile0 = blockIdx.x * TPB + wv * 16;

    for (int ti = 0; ti < 16; ++ti) {
        const int tile = tile0 + ti;
        const int e = tile * 16 + col;
        long long idx = is32 ? (long long)ip[e] : lp[e];
        const float4* s4 = (const float4*)(signal + idx * 32 + quad * 8);
        float4 v0 = s4[0], v1 = s4[1];
        float f[8] = {v0.x, v0.y, v0.z, v0.w, v1.x, v1.y, v1.z, v1.w};
        short8 b0 = pack8(f);
        float g[8] = {0.f, 0.f, 0.f, 0.f, 0.f, 0.f, 0.f, 0.f};
        if (quad == 0) { g[0] = ef[e * 3]; g[1] = ef[e * 3 + 1]; g[2] = ef[e * 3 + 2]; }
        short8 b1 = pack8(g);

        unsigned short* tp = Y + (size_t)tile * 1024;
#pragma unroll
        for (int m = 0; m < 4; ++m) {
            f32x4 acc = {0.f, 0.f, 0.f, 0.f};
            acc = MFMA16(afrag[m][0], b0, acc, 0, 0, 0);
            acc = MFMA16(afrag[m][1], b1, acc, 0, 0, 0);
            *(uint2*)(tp + (m * 2 + (quad >> 1)) * 128 + col * 8 + (quad & 1) * 4) =
                make_uint2(pk2(acc[0], acc[1]), pk2(acc[2], acc[3]));
#pragma unroll
            for (int r = 0; r < 4; ++r) {
                float v = acc[r];
                sacc[m][r] += v;
                s2acc[m][r] = fmaf(v, v, s2acc[m][r]);
            }
        }
    }
    stats_epilogue(sacc, s2acc, tid, wv, col, quad, partials);
}

// ---------------------------------------------------------------------------
// Layers 2/3: in-place TP GEMM: Y[o] = W * lrelu(scale*Y + shift), + stats.
__global__ __launch_bounds__(256) void mfma_stage(
        unsigned short* Y,                      // in-place (no restrict)
        const float* __restrict__ W,            // (64, 64)
        const float* __restrict__ scale,        // (B, 64)
        const float* __restrict__ shift,
        float* __restrict__ partials) {
    const int tid = threadIdx.x, lane = tid & 63, wv = tid >> 6;
    const int col = lane & 15, quad = lane >> 4;
    const int b   = blockIdx.x >> 8;            // 256 blocks per batch

    short8 afrag[4][2];
#pragma unroll
    for (int m = 0; m < 4; ++m)
#pragma unroll
        for (int kc = 0; kc < 2; ++kc) {
            const float4* wp = (const float4*)(W + (m * 16 + col) * 64 + kc * 32 + quad * 8);
            float4 w0 = wp[0], w1 = wp[1];
            float f[8] = {w0.x, w0.y, w0.z, w0.w, w1.x, w1.y, w1.z, w1.w};
            afrag[m][kc] = pack8(f);
        }
    float sc[2][8], sh[2][8];
#pragma unroll
    for (int kc = 0; kc < 2; ++kc) {
        const int c0 = (kc * 4 + quad) * 8;
#pragma unroll
        for (int j = 0; j < 8; ++j) {
            sc[kc][j] = scale[b * COUT + c0 + j];
            sh[kc][j] = shift[b * COUT + c0 + j];
        }
    }
    float sacc[4][4] = {{0.f}}, s2acc[4][4] = {{0.f}};
    const int tile0 = blockIdx.x * TPB + wv * 16;

    for (int ti = 0; ti < 16; ++ti) {
        unsigned short* tp = Y + (size_t)(tile0 + ti) * 1024;
        uint4 r0 = *(const uint4*)(tp + quad * 128 + col * 8);
        uint4 r1 = *(const uint4*)(tp + 512 + quad * 128 + col * 8);
        short8 b0 = xform(r0, sc[0], sh[0]);
        short8 b1 = xform(r1, sc[1], sh[1]);
#pragma unroll
        for (int m = 0; m < 4; ++m) {
            f32x4 acc = {0.f, 0.f, 0.f, 0.f};
            acc = MFMA16(afrag[m][0], b0, acc, 0, 0, 0);
            acc = MFMA16(afrag[m][1], b1, acc, 0, 0, 0);
            *(uint2*)(tp + (m * 2 + (quad >> 1)) * 128 + col * 8 + (quad & 1) * 4) =
                make_uint2(pk2(acc[0], acc[1]), pk2(acc[2], acc[3]));
#pragma unroll
            for (int r = 0; r < 4; ++r) {
                float v = acc[r];
                sacc[m][r] += v;
                s2acc[m][r] = fmaf(v, v, s2acc[m][r]);
            }
        }
    }
    stats_epilogue(sacc, s2acc, tid, wv, col, quad, partials);
}

// ---------------------------------------------------------------------------
// Parallel finalize: one block per (o,b); 256 threads sum that batch's partials.
__global__ __launch_bounds__(256) void finalize_k(
        const float* __restrict__ partials,
        const float* __restrict__ gamma,
        const float* __restrict__ beta,
        float* __restrict__ scale,
        float* __restrict__ shift) {
    const int g = blockIdx.x;        // 0..255
    const int o = g >> 2, b = g & 3;
    const int k = threadIdx.x;       // 0..255
    const float* p = partials + (size_t)(b * 256 + k) * 128 + o * 2;
    float s = p[0], s2 = p[1];
    __shared__ float red[512];
    red[k] = s; red[256 + k] = s2;
    __syncthreads();
    for (int st = 128; st > 0; st >>= 1) {
        if (k < st) { red[k] += red[k + st]; red[256 + k] += red[256 + k + st]; }
        __syncthreads();
    }
    if (k == 0) {
        const float inv_n = 1.f / (float)PERB;
        float mean = red[0] * inv_n;
        float var  = red[256] * inv_n - mean * mean;
        float inv  = rsqrtf(var + EPS);
        float scv  = gamma[o] * inv;
        scale[b * COUT + o] = scv;
        shift[b * COUT + o] = beta[o] - mean * scv;
    }
}

// ---------------------------------------------------------------------------
// Pool: max over K=32 edges (2 TP tiles) per (bn, channel-group), then affine
// + single lrelu (monotone). Thread t -> (bn = t>>3, og = t&7).
__global__ __launch_bounds__(256) void pool_k(
        const unsigned short* __restrict__ Y,
        const float* __restrict__ scale,
        const float* __restrict__ shift,
        float* __restrict__ out) {
    const int t  = blockIdx.x * 256 + threadIdx.x;   // 0..262143
    const int og = t & 7;
    const int bn = t >> 3;
    const int b  = bn >> 13;
    float mx[8], mn[8];
#pragma unroll
    for (int j = 0; j < 8; ++j) { mx[j] = -1e30f; mn[j] = 1e30f; }
#pragma unroll
    for (int half = 0; half < 2; ++half) {
        const unsigned short* p = Y + (size_t)(bn * 2 + half) * 1024 + og * 128;
#pragma unroll
        for (int e = 0; e < 16; ++e) {
            uint4 v = *(const uint4*)(p + e * 8);
            unsigned int w[4] = {v.x, v.y, v.z, v.w};
#pragma unroll
            for (int i = 0; i < 4; ++i) {
                float f0 = bflo(w[i]), f1 = bfhi(w[i]);
                mx[2 * i]     = fmaxf(mx[2 * i], f0);
                mn[2 * i]     = fminf(mn[2 * i], f0);
                mx[2 * i + 1] = fmaxf(mx[2 * i + 1], f1);
                mn[2 * i + 1] = fminf(mn[2 * i + 1], f1);
            }
        }
    }
    float r[8];
#pragma unroll
    for (int j = 0; j < 8; ++j) {
        const int o = og * 8 + j;
        const float s = scale[b * COUT + o], h = shift[b * COUT + o];
        float m = (s >= 0.f ? mx[j] : mn[j]) * s + h;
        r[j] = fmaxf(m, 0.f) + SLOPE * fminf(m, 0.f);
    }
    float4* q = (float4*)(out + (size_t)bn * COUT + og * 8);
    q[0] = make_float4(r[0], r[1], r[2], r[3]);
    q[1] = make_float4(r[4], r[5], r[6], r[7]);
}

// ---------------------------------------------------------------------------
extern "C" void kernel_launch(void* const* d_in, const int* in_sizes, int n_in,
                              void* d_out, int out_size, void* d_ws, size_t ws_size,
                              hipStream_t stream) {
    const float* signal = (const float*)d_in[0];
    const void*  edges  = d_in[1];
    const float* ef     = (const float*)d_in[2];
    const float* W1 = (const float*)d_in[4];
    const float* g1 = (const float*)d_in[5];
    const float* b1 = (const float*)d_in[6];
    const float* W2 = (const float*)d_in[7];
    const float* g2 = (const float*)d_in[8];
    const float* b2 = (const float*)d_in[9];
    const float* W3 = (const float*)d_in[10];
    const float* g3 = (const float*)d_in[11];
    const float* b3 = (const float*)d_in[12];
    float* out = (float*)d_out;

    // Workspace: Y (134.2 MB) + partials (512 KB) + flag + 6x256 scale/shift
    unsigned short* Y = (unsigned short*)d_ws;
    const size_t YB = (size_t)E * COUT * sizeof(unsigned short);
    float* partials = (float*)((char*)d_ws + YB);
    char*  tail = (char*)d_ws + YB + (size_t)BLOCKS * 128 * sizeof(float);
    int*   flag = (int*)tail;
    float* ss   = (float*)(tail + 256);
    float *sc0 = ss,        *sh0 = ss + 256;
    float *sc1 = ss + 512,  *sh1 = ss + 768;
    float *sc2 = ss + 1024, *sh2 = ss + 1280;

    detect_i32<<<1, 64, 0, stream>>>((const unsigned int*)edges, flag);

    mfma_stage1<<<BLOCKS, 256, 0, stream>>>(signal, edges, ef, W1, Y, flag, partials);
    finalize_k<<<256, 256, 0, stream>>>(partials, g1, b1, sc0, sh0);

    mfma_stage<<<BLOCKS, 256, 0, stream>>>(Y, W2, sc0, sh0, partials);
    finalize_k<<<256, 256, 0, stream>>>(partials, g2, b2, sc1, sh1);

    mfma_stage<<<BLOCKS, 256, 0, stream>>>(Y, W3, sc1, sh1, partials);
    finalize_k<<<256, 256, 0, stream>>>(partials, g3, b3, sc2, sh2);

    pool_k<<<1024, 256, 0, stream>>>(Y, sc2, sh2, out);
}